// Round 6
// baseline (594.546 us; speedup 1.0000x reference)
//
#include <hip/hip_runtime.h>
#include <math.h>

#define D 128
#define B 256
#define EPSV 1e-5f

typedef __attribute__((ext_vector_type(8))) short short8;
typedef __attribute__((ext_vector_type(4))) float f32x4;

static __device__ __forceinline__ ushort f2bf(float f) {
  union { float f; unsigned u; } v; v.f = f;
  unsigned r = (v.u + 0x7fffu + ((v.u >> 16) & 1u)) >> 16;
  return (ushort)r;
}
static __device__ __forceinline__ float bf2f(ushort u) {
  union { unsigned u; float f; } v; v.u = ((unsigned)u) << 16; return v.f;
}
// order-preserving float<->uint encoding for atomicMax on floats (handles -inf)
static __device__ __forceinline__ unsigned encf(float f) {
  union { float f; unsigned u; } v; v.f = f;
  return (v.u & 0x80000000u) ? ~v.u : (v.u | 0x80000000u);
}
static __device__ __forceinline__ float decf(unsigned e) {
  union { unsigned u; float f; } v;
  v.u = (e & 0x80000000u) ? (e & 0x7FFFFFFFu) : ~e;
  return v.f;
}
#define ENC_NEGINF 0x007FFFFFu

// ---------------- init: zero node_deg + bn + graph-stat accumulators ----------------
static __global__ void init_kernel(int* node_deg, float* bn1s, float* bn1s2,
                                   float* bn2s, float* bn2s2,
                                   float* gsum, unsigned* gmaxE,
                                   float* gcnt, float* gdsum, unsigned* gdmaxE, int N) {
  int i = blockIdx.x * 256 + threadIdx.x;
  if (i < N) node_deg[i] = 0;
  if (i < D) { bn1s[i] = 0.f; bn1s2[i] = 0.f; bn2s[i] = 0.f; bn2s2[i] = 0.f; }
  if (i < B * D) { gsum[i] = 0.f; gmaxE[i] = ENC_NEGINF; }
  if (i < B) { gcnt[i] = 0.f; gdsum[i] = 0.f; gdmaxE[i] = ENC_NEGINF; }
}

// ---------------- in-degree count over dst ----------------
static __global__ void deg_kernel(const int* __restrict__ dst, int* node_deg, int E) {
  int i = blockIdx.x * 256 + threadIdx.x;
  if (i < E) atomicAdd(&node_deg[dst[i]], 1);
}

// ---------------- node-parallel feature stats + x->bf16 copy ----------------
static __global__ void statspart_kernel(const float* __restrict__ x, const int* __restrict__ batch,
                                        float* gsum, unsigned* gmaxE,
                                        ushort* __restrict__ x_bf, int N) {
  int t = threadIdx.x;  // 128
  int n0 = blockIdx.x * 64;
  int nend = min(n0 + 64, N);
  int curg = batch[n0];
  float s = 0.f, mx = -INFINITY;
  for (int n = n0; n < nend; n++) {
    int g = batch[n];  // block-uniform branch (batch sorted)
    if (g != curg) {
      atomicAdd(&gsum[curg * D + t], s);
      atomicMax(&gmaxE[curg * D + t], encf(mx));
      s = 0.f; mx = -INFINITY; curg = g;
    }
    float v = x[(size_t)n * D + t];
    x_bf[(size_t)n * D + t] = f2bf(v);
    s += v; mx = fmaxf(mx, v);
  }
  atomicAdd(&gsum[curg * D + t], s);
  atomicMax(&gmaxE[curg * D + t], encf(mx));
}

// ---------------- router MLP + temperature softmax -> gates[B][4] ----------------
static __global__ void router_kernel(
    const float* __restrict__ gsum, const unsigned* __restrict__ gmaxE,
    const float* __restrict__ gcnt, const float* __restrict__ gdsum,
    const unsigned* __restrict__ gdmaxE,
    const float* __restrict__ rw1, const float* __restrict__ rb1,
    const float* __restrict__ rw2, const float* __restrict__ rb2,
    const float* __restrict__ rw3, const float* __restrict__ rb3,
    const float* __restrict__ temp, float* __restrict__ gates) {
  int g = blockIdx.x, t = threadIdx.x;  // 128 threads
  __shared__ float geS[260], h1S[D], h2S[64], scS[4];
  float cntf = fmaxf(gcnt[g], 1.f);
  geS[t] = gsum[g * D + t] / cntf;       // mean pool
  geS[D + t] = decf(gmaxE[g * D + t]);   // max pool
  if (t == 0) {
    geS[256] = cntf;
    geS[257] = gdsum[g] / cntf;
    geS[258] = decf(gdmaxE[g]);
    geS[259] = logf(cntf);
  }
  __syncthreads();
  float a = rb1[t];
  for (int k = 0; k < 260; k++) a += geS[k] * rw1[k * D + t];
  h1S[t] = fmaxf(a, 0.f);
  __syncthreads();
  if (t < 64) { float b = rb2[t]; for (int k = 0; k < D; k++) b += h1S[k] * rw2[k * 64 + t]; h2S[t] = fmaxf(b, 0.f); }
  __syncthreads();
  if (t < 4) { float c = rb3[t]; for (int k = 0; k < 64; k++) c += h2S[k] * rw3[k * 4 + t]; scS[t] = c; }
  __syncthreads();
  if (t == 0) {
    float T = temp[0];
    float q0 = scS[0] / T, q1 = scS[1] / T, q2 = scS[2] / T, q3 = scS[3] / T;
    float m = fmaxf(fmaxf(q0, q1), fmaxf(q2, q3));
    float e0 = expf(q0 - m), e1 = expf(q1 - m), e2 = expf(q2 - m), e3 = expf(q3 - m);
    float inv = 1.f / (e0 + e1 + e2 + e3);
    gates[g * 4 + 0] = e0 * inv; gates[g * 4 + 1] = e1 * inv;
    gates[g * 4 + 2] = e2 * inv; gates[g * 4 + 3] = e3 * inv;
  }
}

// ---------------- per-graph combined expert weights, bf16 TRANSPOSED ----------------
static __global__ void __launch_bounds__(256) wcomb_kernel(
    const float* __restrict__ gates, const float* __restrict__ ew,
    const float* __restrict__ eb, ushort* __restrict__ W_combT,
    float* __restrict__ b_comb) {
  __shared__ ushort wS[128 * 130];
  int g = blockIdx.x, t = threadIdx.x;  // 256 threads
  float g0 = gates[g * 4], g1 = gates[g * 4 + 1], g2 = gates[g * 4 + 2], g3 = gates[g * 4 + 3];
  for (int k = t; k < D * D; k += 256) {
    int d = k >> 7, o = k & 127;  // coalesced read over o
    float v = g0 * ew[k] + g1 * ew[16384 + k] + g2 * ew[32768 + k] + g3 * ew[49152 + k];
    wS[o * 130 + d] = f2bf(v);
  }
  __syncthreads();
  for (int k = t; k < D * D; k += 256) {
    int o = k >> 7, d = k & 127;  // coalesced write over d
    W_combT[(size_t)g * 16384 + k] = wS[o * 130 + d];
  }
  if (t < D)
    b_comb[g * D + t] = g0 * eb[t] + g1 * eb[D + t] + g2 * eb[2 * D + t] + g3 * eb[3 * D + t];
}

// ---------------- FFN weights -> bf16 transposed (k-contiguous) ----------------
static __global__ void prep_kernel(const float* __restrict__ w1, const float* __restrict__ w2,
                                   ushort* __restrict__ w1t, ushort* __restrict__ w2t) {
  int i = blockIdx.x * 256 + threadIdx.x;  // 32768 total
  { int j = i >> 7, d = i & 127; w1t[i] = f2bf(w1[(size_t)d * 256 + j]); }
  { int o = i >> 8, j = i & 255; w2t[i] = f2bf(w2[(size_t)j * 128 + o]); }
}

// ---------------- 3-phase prefix scan of node_deg -> rowoff, plus dinv + bucket bases ----------------
static __global__ void scanA_kernel(const int* __restrict__ node_deg, int* rowoff, int* blocksum, int N) {
  __shared__ int sS[1024];
  int t = threadIdx.x, i = blockIdx.x * 1024 + t;
  int v = (i < N) ? node_deg[i] : 0;
  sS[t] = v; __syncthreads();
  for (int off = 1; off < 1024; off <<= 1) {
    int add = (t >= off) ? sS[t - off] : 0;
    __syncthreads();
    sS[t] += add;
    __syncthreads();
  }
  if (i < N) rowoff[i + 1] = sS[t];
  if (t == 1023) blocksum[blockIdx.x] = sS[1023];
}

static __global__ void scanB_kernel(const int* __restrict__ blocksum, int* blockbase, int nb) {
  __shared__ int sS[128];
  int t = threadIdx.x;
  int v = (t < nb) ? blocksum[t] : 0;
  sS[t] = v; __syncthreads();
  for (int off = 1; off < 128; off <<= 1) {
    int add = (t >= off) ? sS[t - off] : 0;
    __syncthreads();
    sS[t] += add;
    __syncthreads();
  }
  blockbase[t] = sS[t] - v;  // exclusive
}

// finalizes rowoff; writes bucket cursors; folds per-graph degree stats
static __global__ void scanC_kernel(const int* __restrict__ node_deg, int* rowoff,
                                    const int* __restrict__ blockbase,
                                    float* dinv, const int* __restrict__ batch,
                                    int* bcur,
                                    float* gcnt, float* gdsum, unsigned* gdmaxE, int N) {
  int i = blockIdx.x * 256 + threadIdx.x;
  int nd = 0;
  if (i < N) {
    int incl = rowoff[i + 1] + blockbase[i >> 10];
    rowoff[i + 1] = incl;
    nd = node_deg[i];
    dinv[i] = rsqrtf((float)nd + 1.0f);
    if (i == 0) { rowoff[0] = 0; bcur[0] = 0; }
    if (((i + 1) & 511) == 0) bcur[(i + 1) >> 9] = incl;
  }
  int g = batch[min(i, N - 1)];
  float dv = (float)nd;
  int g0w = __shfl(g, 0);
  int waveLast = blockIdx.x * 256 + ((threadIdx.x >> 6) << 6) + 63;
  bool uni = (waveLast < N) && __all(g == g0w);
  if (uni) {
    float s = dv, mx = dv;
    for (int off = 32; off > 0; off >>= 1) { s += __shfl_down(s, off); mx = fmaxf(mx, __shfl_down(mx, off)); }
    if ((threadIdx.x & 63) == 0) {
      atomicAdd(&gcnt[g0w], 64.f);
      atomicAdd(&gdsum[g0w], s);
      atomicMax(&gdmaxE[g0w], encf(mx));
    }
  } else if (i < N) {
    atomicAdd(&gcnt[g], 1.f);
    atomicAdd(&gdsum[g], dv);
    atomicMax(&gdmaxE[g], encf(dv));
  }
}

// ---------------- CSR build pass A: coarse bucket sort by dst>>9, packed int ----------------
// packed edge = (src<<9) | (dst & 511). Assumes NB <= 256 (N <= 131072).
static __global__ void __launch_bounds__(256) fillA_kernel(
    const int* __restrict__ src, const int* __restrict__ dst,
    int* bcur, int* __restrict__ esort, int E) {
  __shared__ int histS[256], startS[256], cursorS[256], gbaseS[256];
  __shared__ int eS[4096];             // 16 KB packed
  __shared__ unsigned char bS[4096];   // bucket of each slot
  int t = threadIdx.x;
  int base = blockIdx.x * 4096;
  int cnt = min(4096, E - base);
  int srcR[16], dstR[16];
  histS[t] = 0;
  __syncthreads();
#pragma unroll
  for (int k = 0; k < 16; k++) {
    int e = base + k * 256 + t;
    if (e < E) { srcR[k] = src[e]; dstR[k] = dst[e]; }
    else dstR[k] = -1;
  }
#pragma unroll
  for (int k = 0; k < 16; k++)
    if (dstR[k] >= 0) atomicAdd(&histS[dstR[k] >> 9], 1);
  __syncthreads();
  int hv = histS[t];
  startS[t] = hv;
  __syncthreads();
  for (int off = 1; off < 256; off <<= 1) {
    int add = (t >= off) ? startS[t - off] : 0;
    __syncthreads();
    startS[t] += add;
    __syncthreads();
  }
  int excl = startS[t] - hv;
  __syncthreads();
  startS[t] = excl;
  cursorS[t] = excl;
  gbaseS[t] = (hv > 0) ? atomicAdd(&bcur[t], hv) : 0;
  __syncthreads();
#pragma unroll
  for (int k = 0; k < 16; k++)
    if (dstR[k] >= 0) {
      int b = dstR[k] >> 9;
      int p = atomicAdd(&cursorS[b], 1);
      eS[p] = (srcR[k] << 9) | (dstR[k] & 511);
      bS[p] = (unsigned char)b;
    }
  __syncthreads();
  for (int k = t; k < cnt; k += 256) {
    int b = bS[k];
    esort[gbaseS[b] + (k - startS[b])] = eS[k];
  }
}

// ---------------- CSR build pass B: per-bucket fine fill, LDS cursors ----------------
static __global__ void __launch_bounds__(256) fillB_kernel(
    const int* __restrict__ esort, const int* __restrict__ rowoff,
    int* __restrict__ csr_src, int N) {
  __shared__ int curS[512];
  int b = blockIdx.x, t = threadIdx.x;
  int n0 = b << 9, n1 = min(n0 + 512, N);
  int nn = n1 - n0;
  for (int i = t; i < nn; i += 256) curS[i] = rowoff[n0 + i];
  int r0 = rowoff[n0], r1 = rowoff[n1];
  __syncthreads();
  for (int e = r0 + t; e < r1; e += 256) {
    int v = esort[e];
    int p = atomicAdd(&curS[v & 511], 1);
    csr_src[p] = v >> 9;
  }
}

// ---------------- GCN aggregation: one WAVE per node, bf16 rows, 4-deep unroll ----------------
static __global__ void __launch_bounds__(256) gather_kernel(
    const ushort2* __restrict__ xb2, const int* __restrict__ rowoff,
    const int* __restrict__ csr_src, const float* __restrict__ dinv,
    ushort2* __restrict__ aggB2, int N) {
  __shared__ int eS[4][64];
  __shared__ float cS[4][64];
  int t = threadIdx.x, w = t >> 6, l = t & 63;
  int n = blockIdx.x * 4 + w;
  if (n >= N) return;
  int r0 = rowoff[n], r1 = rowoff[n + 1];
  float dn = dinv[n];
  ushort2 xv = xb2[(size_t)n * 64 + l];
  float2 acc = { bf2f(xv.x) * dn, bf2f(xv.y) * dn };
  for (int j0 = r0; j0 < r1; j0 += 64) {
    int cnt = min(64, r1 - j0);
    if (j0 + l < r1) { int s = csr_src[j0 + l]; eS[w][l] = s; cS[w][l] = dinv[s]; }
    int k = 0;
    for (; k + 4 <= cnt; k += 4) {  // 4 independent row loads in flight
      int s0 = eS[w][k], s1 = eS[w][k + 1], s2 = eS[w][k + 2], s3 = eS[w][k + 3];
      float c0 = cS[w][k], c1 = cS[w][k + 1], c2 = cS[w][k + 2], c3 = cS[w][k + 3];
      ushort2 v0 = xb2[(size_t)s0 * 64 + l];
      ushort2 v1 = xb2[(size_t)s1 * 64 + l];
      ushort2 v2 = xb2[(size_t)s2 * 64 + l];
      ushort2 v3 = xb2[(size_t)s3 * 64 + l];
      acc.x += bf2f(v0.x) * c0; acc.y += bf2f(v0.y) * c0;
      acc.x += bf2f(v1.x) * c1; acc.y += bf2f(v1.y) * c1;
      acc.x += bf2f(v2.x) * c2; acc.y += bf2f(v2.y) * c2;
      acc.x += bf2f(v3.x) * c3; acc.y += bf2f(v3.y) * c3;
    }
    for (; k < cnt; k++) {
      int s = eS[w][k]; float cc = cS[w][k];
      ushort2 sv = xb2[(size_t)s * 64 + l];
      acc.x += bf2f(sv.x) * cc; acc.y += bf2f(sv.y) * cc;
    }
  }
  ushort2 o; o.x = f2bf(acc.x * dn); o.y = f2bf(acc.y * dn);
  aggB2[(size_t)n * 64 + l] = o;
}

// ---------------- gated expert combine + residual (MFMA bf16) ----------------
// aggB (bf16) in, hB (bf16) out. BN1 sums from fp32 pre-round values.
static __global__ void __launch_bounds__(256) expert_kernel(
    const ushort* __restrict__ aggB, const float* __restrict__ x, const int* __restrict__ batch,
    const ushort* __restrict__ W_combT, const float* __restrict__ b_comb,
    ushort* __restrict__ hB, float* bn1s, float* bn1s2, int N) {
  __shared__ __align__(16) ushort aggS[64 * 136];
  __shared__ int bS[64];
  int t = threadIdx.x, n0 = blockIdx.x * 64;
  int tile = min(64, N - n0);
  for (int k = t; k < 64 * 16; k += 256) {  // short8 copies, no convert
    int i = k >> 4, c = (k & 15) * 8;
    short8 v = (short8){0, 0, 0, 0, 0, 0, 0, 0};
    if (i < tile) v = *(const short8*)&aggB[(size_t)(n0 + i) * D + c];
    *(short8*)&aggS[i * 136 + c] = v;
  }
  if (t < 64) bS[t] = batch[min(n0 + t, N - 1)];
  __syncthreads();
  int w = t >> 6, ln = t & 15, quad = (t & 63) >> 4;
  float s[2] = {0.f, 0.f}, s2[2] = {0.f, 0.f};
  int mstart = 0;
  while (mstart < tile) {
    int g = bS[mstart];
    int mend = mstart + 1;
    while (mend < tile && bS[mend] == g) mend++;
    f32x4 acc[4][2];
#pragma unroll
    for (int mi = 0; mi < 4; mi++)
#pragma unroll
      for (int ni = 0; ni < 2; ni++) acc[mi][ni] = (f32x4){0.f, 0.f, 0.f, 0.f};
    const ushort* Wg = W_combT + (size_t)g * 16384;
#pragma unroll
    for (int ks = 0; ks < 4; ks++) {
      int kk = ks * 32 + quad * 8;
      short8 a[4], b[2];
#pragma unroll
      for (int mi = 0; mi < 4; mi++) a[mi] = *(const short8*)&aggS[(mi * 16 + ln) * 136 + kk];
#pragma unroll
      for (int ni = 0; ni < 2; ni++) b[ni] = *(const short8*)&Wg[(size_t)(w * 32 + ni * 16 + ln) * 128 + kk];
#pragma unroll
      for (int mi = 0; mi < 4; mi++)
#pragma unroll
        for (int ni = 0; ni < 2; ni++)
          acc[mi][ni] = __builtin_amdgcn_mfma_f32_16x16x32_bf16(a[mi], b[ni], acc[mi][ni], 0, 0, 0);
    }
    float bias[2];
#pragma unroll
    for (int ni = 0; ni < 2; ni++) bias[ni] = b_comb[g * D + w * 32 + ni * 16 + ln];
#pragma unroll
    for (int mi = 0; mi < 4; mi++)
#pragma unroll
      for (int r = 0; r < 4; r++) {
        int m = mi * 16 + quad * 4 + r;
        if (m >= mstart && m < mend) {
          size_t rowoff_ = (size_t)(n0 + m) * D;
#pragma unroll
          for (int ni = 0; ni < 2; ni++) {
            int o = w * 32 + ni * 16 + ln;
            float hv = x[rowoff_ + o] + acc[mi][ni][r] + bias[ni];
            hB[rowoff_ + o] = f2bf(hv);
            s[ni] += hv; s2[ni] += hv * hv;
          }
        }
      }
    mstart = mend;
  }
#pragma unroll
  for (int ni = 0; ni < 2; ni++) {
    s[ni] += __shfl_down(s[ni], 32);  s[ni] += __shfl_down(s[ni], 16);
    s2[ni] += __shfl_down(s2[ni], 32); s2[ni] += __shfl_down(s2[ni], 16);
  }
  if (quad == 0) {
#pragma unroll
    for (int ni = 0; ni < 2; ni++) {
      int o = w * 32 + ni * 16 + ln;
      atomicAdd(&bn1s[o], s[ni]);
      atomicAdd(&bn1s2[o], s2[ni]);
    }
  }
}

// ---------------- bn finalize: mu/var -> fused scale/shift ----------------
static __global__ void bnfin_kernel(const float* s, const float* s2,
                                    const float* __restrict__ g, const float* __restrict__ b,
                                    float* sc, float* sh, float invN) {
  int t = threadIdx.x;
  if (t < D) {
    float m = s[t] * invN;
    float var = s2[t] * invN - m * m;
    float rstd = rsqrtf(var + EPSV);
    float scv = rstd * g[t];
    sc[t] = scv;
    sh[t] = b[t] - m * scv;
  }
}

// ---------------- FFN (MFMA bf16), M=32 tile for occupancy, in-place on hB ----------------
// LDS 25.6 KB -> 6 blocks/CU (vs 52 KB -> 3). Serial chain hidden by TLP.
static __global__ void __launch_bounds__(256) ffn_kernel(
    ushort* __restrict__ hB, const float* __restrict__ sc1, const float* __restrict__ sh1,
    const ushort* __restrict__ w1t, const float* __restrict__ fb1,
    const ushort* __restrict__ w2t, const float* __restrict__ fb2,
    float* bn2s, float* bn2s2, int N) {
  __shared__ __align__(16) ushort kvnS[32 * 136];   // 8.7 KB
  __shared__ __align__(16) ushort hidS[32 * 264];   // 16.9 KB
  int t = threadIdx.x, n0 = blockIdx.x * 32;
  int tile = min(32, N - n0);
  for (int k = t; k < 32 * 64; k += 256) {
    int i = k >> 6, dp = (k & 63) * 2;
    float vx = 0.f, vy = 0.f;
    if (i < tile) {
      ushort2 hv = *(const ushort2*)&hB[(size_t)(n0 + i) * D + dp];
      vx = bf2f(hv.x) * sc1[dp] + sh1[dp];
      vy = bf2f(hv.y) * sc1[dp + 1] + sh1[dp + 1];
    }
    kvnS[i * 136 + dp] = f2bf(vx);
    kvnS[i * 136 + dp + 1] = f2bf(vy);
  }
  __syncthreads();
  int w = t >> 6, ln = t & 15, quad = (t & 63) >> 4;
  // ---- GEMM1: hidden[32x256] = kvn[32x128] @ w1[128x256]
  f32x4 acc1[2][4];
#pragma unroll
  for (int mi = 0; mi < 2; mi++)
#pragma unroll
    for (int ni = 0; ni < 4; ni++) acc1[mi][ni] = (f32x4){0.f, 0.f, 0.f, 0.f};
#pragma unroll
  for (int ks = 0; ks < 4; ks++) {
    int kk = ks * 32 + quad * 8;
    short8 a[2], b[4];
#pragma unroll
    for (int mi = 0; mi < 2; mi++) a[mi] = *(const short8*)&kvnS[(mi * 16 + ln) * 136 + kk];
#pragma unroll
    for (int ni = 0; ni < 4; ni++) b[ni] = *(const short8*)&w1t[(size_t)(w * 64 + ni * 16 + ln) * 128 + kk];
#pragma unroll
    for (int mi = 0; mi < 2; mi++)
#pragma unroll
      for (int ni = 0; ni < 4; ni++)
        acc1[mi][ni] = __builtin_amdgcn_mfma_f32_16x16x32_bf16(a[mi], b[ni], acc1[mi][ni], 0, 0, 0);
  }
  float bias1[4];
#pragma unroll
  for (int ni = 0; ni < 4; ni++) bias1[ni] = fb1[w * 64 + ni * 16 + ln];
#pragma unroll
  for (int mi = 0; mi < 2; mi++)
#pragma unroll
    for (int ni = 0; ni < 4; ni++)
#pragma unroll
      for (int r = 0; r < 4; r++) {
        int mrow = mi * 16 + quad * 4 + r;
        int j = w * 64 + ni * 16 + ln;
        hidS[mrow * 264 + j] = f2bf(fmaxf(acc1[mi][ni][r] + bias1[ni], 0.f));
      }
  __syncthreads();
  // ---- GEMM2: out[32x128] = hidden[32x256] @ w2[256x128]
  f32x4 acc2[2][2];
#pragma unroll
  for (int mi = 0; mi < 2; mi++)
#pragma unroll
    for (int ni = 0; ni < 2; ni++) acc2[mi][ni] = (f32x4){0.f, 0.f, 0.f, 0.f};
#pragma unroll
  for (int ks = 0; ks < 8; ks++) {
    int kk = ks * 32 + quad * 8;
    short8 a[2], b[2];
#pragma unroll
    for (int mi = 0; mi < 2; mi++) a[mi] = *(const short8*)&hidS[(mi * 16 + ln) * 264 + kk];
#pragma unroll
    for (int ni = 0; ni < 2; ni++) b[ni] = *(const short8*)&w2t[(size_t)(w * 32 + ni * 16 + ln) * 256 + kk];
#pragma unroll
    for (int mi = 0; mi < 2; mi++)
#pragma unroll
      for (int ni = 0; ni < 2; ni++)
        acc2[mi][ni] = __builtin_amdgcn_mfma_f32_16x16x32_bf16(a[mi], b[ni], acc2[mi][ni], 0, 0, 0);
  }
  float bias2[2];
#pragma unroll
  for (int ni = 0; ni < 2; ni++) bias2[ni] = fb2[w * 32 + ni * 16 + ln];
  float s[2] = {0.f, 0.f}, s2[2] = {0.f, 0.f};
#pragma unroll
  for (int mi = 0; mi < 2; mi++)
#pragma unroll
    for (int r = 0; r < 4; r++) {
      int mrow = mi * 16 + quad * 4 + r;
      if (mrow < tile) {
        size_t rowoff_ = (size_t)(n0 + mrow) * D;
#pragma unroll
        for (int ni = 0; ni < 2; ni++) {
          int o = w * 32 + ni * 16 + ln;
          float v = bf2f(kvnS[mrow * 136 + o]) + acc2[mi][ni][r] + bias2[ni];
          hB[rowoff_ + o] = f2bf(v);  // in-place: tile already staged in kvnS
          s[ni] += v; s2[ni] += v * v;
        }
      }
    }
#pragma unroll
  for (int ni = 0; ni < 2; ni++) {
    s[ni] += __shfl_down(s[ni], 32);  s[ni] += __shfl_down(s[ni], 16);
    s2[ni] += __shfl_down(s2[ni], 32); s2[ni] += __shfl_down(s2[ni], 16);
  }
  if (quad == 0) {
#pragma unroll
    for (int ni = 0; ni < 2; ni++) {
      int o = w * 32 + ni * 16 + ln;
      atomicAdd(&bn2s[o], s[ni]);
      atomicAdd(&bn2s2[o], s2[ni]);
    }
  }
}

// ---------------- final bn2 apply: bf16 in -> fp32 out, fused scale/shift ----------------
static __global__ void bnapply_kernel(const ushort* __restrict__ hB, float* __restrict__ out,
                                      const float* __restrict__ sc, const float* __restrict__ sh,
                                      int total) {
  int i = blockIdx.x * 256 + threadIdx.x;
  if (i < total) {
    int d = i & 127;
    out[i] = bf2f(hB[i]) * sc[d] + sh[d];
  }
}

extern "C" void kernel_launch(void* const* d_in, const int* in_sizes, int n_in,
                              void* d_out, int out_size, void* d_ws, size_t ws_size,
                              hipStream_t stream) {
  (void)n_in; (void)out_size; (void)ws_size;
  const float* x    = (const float*)d_in[0];
  const int*   ei   = (const int*)d_in[1];
  const int*   batch= (const int*)d_in[2];
  const float* temp = (const float*)d_in[3];
  const float* rw1  = (const float*)d_in[4];
  const float* rb1  = (const float*)d_in[5];
  const float* rw2  = (const float*)d_in[6];
  const float* rb2  = (const float*)d_in[7];
  const float* rw3  = (const float*)d_in[8];
  const float* rb3  = (const float*)d_in[9];
  const float* ew   = (const float*)d_in[10];
  const float* eb   = (const float*)d_in[11];
  const float* bn1g = (const float*)d_in[12];
  const float* bn1b = (const float*)d_in[13];
  const float* fw1  = (const float*)d_in[14];
  const float* fb1  = (const float*)d_in[15];
  const float* fw2  = (const float*)d_in[16];
  const float* fb2  = (const float*)d_in[17];
  const float* bn2g = (const float*)d_in[18];
  const float* bn2b = (const float*)d_in[19];

  int N = in_sizes[0] / D;
  int E = in_sizes[1] / 2;
  const int* src = ei;
  const int* dst = ei + E;

  // d_out doubles as scratch: x_bf | aggB (2 x N*D*2 bytes = exactly out size);
  // both dead before bnapply overwrites d_out with the fp32 result.
  ushort* x_bf = (ushort*)d_out;
  ushort* aggB = (ushort*)((char*)d_out + (size_t)N * D * 2);

  char* p = (char*)d_ws;
  auto alloc = [&](size_t bytes) -> void* {
    void* r = (void*)p;
    p += (bytes + 255) & ~(size_t)255;
    return r;
  };
  int NB = (N + 511) >> 9;  // 512-node buckets (assumes NB <= 256)
  int*   node_deg = (int*)alloc((size_t)N * 4);
  int*   rowoff   = (int*)alloc(((size_t)N + 1) * 4);
  int*   csr_src  = (int*)alloc((size_t)E * 4);
  int*   esort    = (int*)alloc((size_t)E * 4);
  int*   bcur     = (int*)alloc(((size_t)NB + 1) * 4);
  int*   blocksum = (int*)alloc(128 * 4);
  int*   blockbase= (int*)alloc(128 * 4);
  float* dinv     = (float*)alloc((size_t)N * 4);
  ushort* hB      = (ushort*)alloc((size_t)N * D * 2);
  float* gsum     = (float*)alloc((size_t)B * D * 4);
  unsigned* gmaxE = (unsigned*)alloc((size_t)B * D * 4);
  float* gcnt     = (float*)alloc((size_t)B * 4);
  float* gdsum    = (float*)alloc((size_t)B * 4);
  unsigned* gdmaxE= (unsigned*)alloc((size_t)B * 4);
  float* gates    = (float*)alloc((size_t)B * 4 * 4);
  float* b_comb   = (float*)alloc((size_t)B * D * 4);
  float* bn1s     = (float*)alloc(D * 4);
  float* bn1s2    = (float*)alloc(D * 4);
  float* sc1      = (float*)alloc(D * 4);
  float* sh1      = (float*)alloc(D * 4);
  float* bn2s     = (float*)alloc(D * 4);
  float* bn2s2    = (float*)alloc(D * 4);
  float* sc2      = (float*)alloc(D * 4);
  float* sh2      = (float*)alloc(D * 4);
  ushort* W_combT = (ushort*)alloc((size_t)B * D * D * 2);
  ushort* w1t     = (ushort*)alloc((size_t)D * 256 * 2);
  ushort* w2t     = (ushort*)alloc((size_t)D * 256 * 2);

  init_kernel<<<(N + 255) / 256, 256, 0, stream>>>(node_deg, bn1s, bn1s2, bn2s, bn2s2,
                                                   gsum, gmaxE, gcnt, gdsum, gdmaxE, N);
  deg_kernel<<<(E + 255) / 256, 256, 0, stream>>>(dst, node_deg, E);
  prep_kernel<<<128, 256, 0, stream>>>(fw1, fw2, w1t, w2t);
  statspart_kernel<<<(N + 63) / 64, 128, 0, stream>>>(x, batch, gsum, gmaxE, x_bf, N);
  int nb = (N + 1023) / 1024;
  scanA_kernel<<<nb, 1024, 0, stream>>>(node_deg, rowoff, blocksum, N);
  scanB_kernel<<<1, 128, 0, stream>>>(blocksum, blockbase, nb);
  scanC_kernel<<<(N + 255) / 256, 256, 0, stream>>>(node_deg, rowoff, blockbase, dinv,
                                                    batch, bcur, gcnt, gdsum, gdmaxE, N);
  router_kernel<<<B, 128, 0, stream>>>(gsum, gmaxE, gcnt, gdsum, gdmaxE,
                                       rw1, rb1, rw2, rb2, rw3, rb3, temp, gates);
  wcomb_kernel<<<B, 256, 0, stream>>>(gates, ew, eb, W_combT, b_comb);
  fillA_kernel<<<(E + 4095) / 4096, 256, 0, stream>>>(src, dst, bcur, esort, E);
  fillB_kernel<<<NB, 256, 0, stream>>>(esort, rowoff, csr_src, N);
  gather_kernel<<<(N + 3) / 4, 256, 0, stream>>>((const ushort2*)x_bf, rowoff, csr_src, dinv,
                                                 (ushort2*)aggB, N);
  int nb64 = (N + 63) / 64;
  expert_kernel<<<nb64, 256, 0, stream>>>(aggB, x, batch, W_combT, b_comb, hB, bn1s, bn1s2, N);
  bnfin_kernel<<<1, 128, 0, stream>>>(bn1s, bn1s2, bn1g, bn1b, sc1, sh1, 1.0f / (float)N);
  int nb32 = (N + 31) / 32;
  ffn_kernel<<<nb32, 256, 0, stream>>>(hB, sc1, sh1, w1t, fb1, w2t, fb2, bn2s, bn2s2, N);
  bnfin_kernel<<<1, 128, 0, stream>>>(bn2s, bn2s2, bn2g, bn2b, sc2, sh2, 1.0f / (float)N);
  bnapply_kernel<<<((size_t)N * D + 255) / 256, 256, 0, stream>>>(hB, (float*)d_out, sc2, sh2, N * D);
}

// Round 7
// 529.780 us; speedup vs baseline: 1.1223x; 1.1223x over previous
//
#include <hip/hip_runtime.h>
#include <math.h>

#define D 128
#define B 256
#define EPSV 1e-5f
#define NREP 64   // BN accumulator replicas (atomic-contention spread)

typedef __attribute__((ext_vector_type(8))) short short8;
typedef __attribute__((ext_vector_type(4))) float f32x4;

static __device__ __forceinline__ ushort f2bf(float f) {
  union { float f; unsigned u; } v; v.f = f;
  unsigned r = (v.u + 0x7fffu + ((v.u >> 16) & 1u)) >> 16;
  return (ushort)r;
}
static __device__ __forceinline__ float bf2f(ushort u) {
  union { unsigned u; float f; } v; v.u = ((unsigned)u) << 16; return v.f;
}
// order-preserving float<->uint encoding for atomicMax on floats (handles -inf)
static __device__ __forceinline__ unsigned encf(float f) {
  union { float f; unsigned u; } v; v.f = f;
  return (v.u & 0x80000000u) ? ~v.u : (v.u | 0x80000000u);
}
static __device__ __forceinline__ float decf(unsigned e) {
  union { unsigned u; float f; } v;
  v.u = (e & 0x80000000u) ? (e & 0x7FFFFFFFu) : ~e;
  return v.f;
}
#define ENC_NEGINF 0x007FFFFFu

// ---------------- init: zero node_deg + bn + graph-stat accumulators ----------------
static __global__ void init_kernel(int* node_deg, float* bn1s, float* bn1s2,
                                   float* bn2s, float* bn2s2,
                                   float* gsum, unsigned* gmaxE,
                                   float* gcnt, float* gdsum, unsigned* gdmaxE, int N) {
  int i = blockIdx.x * 256 + threadIdx.x;
  if (i < N) node_deg[i] = 0;
  if (i < NREP * D) { bn1s[i] = 0.f; bn1s2[i] = 0.f; bn2s[i] = 0.f; bn2s2[i] = 0.f; }
  if (i < B * D) { gsum[i] = 0.f; gmaxE[i] = ENC_NEGINF; }
  if (i < B) { gcnt[i] = 0.f; gdsum[i] = 0.f; gdmaxE[i] = ENC_NEGINF; }
}

// ---------------- in-degree count over dst ----------------
static __global__ void deg_kernel(const int* __restrict__ dst, int* node_deg, int E) {
  int i = blockIdx.x * 256 + threadIdx.x;
  if (i < E) atomicAdd(&node_deg[dst[i]], 1);
}

// ---------------- node-parallel feature stats + x->bf16 copy ----------------
static __global__ void statspart_kernel(const float* __restrict__ x, const int* __restrict__ batch,
                                        float* gsum, unsigned* gmaxE,
                                        ushort* __restrict__ x_bf, int N) {
  int t = threadIdx.x;  // 128
  int n0 = blockIdx.x * 64;
  int nend = min(n0 + 64, N);
  int curg = batch[n0];
  float s = 0.f, mx = -INFINITY;
  for (int n = n0; n < nend; n++) {
    int g = batch[n];  // block-uniform branch (batch sorted)
    if (g != curg) {
      atomicAdd(&gsum[curg * D + t], s);
      atomicMax(&gmaxE[curg * D + t], encf(mx));
      s = 0.f; mx = -INFINITY; curg = g;
    }
    float v = x[(size_t)n * D + t];
    x_bf[(size_t)n * D + t] = f2bf(v);
    s += v; mx = fmaxf(mx, v);
  }
  atomicAdd(&gsum[curg * D + t], s);
  atomicMax(&gmaxE[curg * D + t], encf(mx));
}

// ---------------- router MLP + temperature softmax -> gates[B][4] ----------------
static __global__ void router_kernel(
    const float* __restrict__ gsum, const unsigned* __restrict__ gmaxE,
    const float* __restrict__ gcnt, const float* __restrict__ gdsum,
    const unsigned* __restrict__ gdmaxE,
    const float* __restrict__ rw1, const float* __restrict__ rb1,
    const float* __restrict__ rw2, const float* __restrict__ rb2,
    const float* __restrict__ rw3, const float* __restrict__ rb3,
    const float* __restrict__ temp, float* __restrict__ gates) {
  int g = blockIdx.x, t = threadIdx.x;  // 128 threads
  __shared__ float geS[260], h1S[D], h2S[64], scS[4];
  float cntf = fmaxf(gcnt[g], 1.f);
  geS[t] = gsum[g * D + t] / cntf;       // mean pool
  geS[D + t] = decf(gmaxE[g * D + t]);   // max pool
  if (t == 0) {
    geS[256] = cntf;
    geS[257] = gdsum[g] / cntf;
    geS[258] = decf(gdmaxE[g]);
    geS[259] = logf(cntf);
  }
  __syncthreads();
  float a = rb1[t];
  for (int k = 0; k < 260; k++) a += geS[k] * rw1[k * D + t];
  h1S[t] = fmaxf(a, 0.f);
  __syncthreads();
  if (t < 64) { float b = rb2[t]; for (int k = 0; k < D; k++) b += h1S[k] * rw2[k * 64 + t]; h2S[t] = fmaxf(b, 0.f); }
  __syncthreads();
  if (t < 4) { float c = rb3[t]; for (int k = 0; k < 64; k++) c += h2S[k] * rw3[k * 4 + t]; scS[t] = c; }
  __syncthreads();
  if (t == 0) {
    float T = temp[0];
    float q0 = scS[0] / T, q1 = scS[1] / T, q2 = scS[2] / T, q3 = scS[3] / T;
    float m = fmaxf(fmaxf(q0, q1), fmaxf(q2, q3));
    float e0 = expf(q0 - m), e1 = expf(q1 - m), e2 = expf(q2 - m), e3 = expf(q3 - m);
    float inv = 1.f / (e0 + e1 + e2 + e3);
    gates[g * 4 + 0] = e0 * inv; gates[g * 4 + 1] = e1 * inv;
    gates[g * 4 + 2] = e2 * inv; gates[g * 4 + 3] = e3 * inv;
  }
}

// ---------------- per-graph combined expert weights, bf16 TRANSPOSED ----------------
static __global__ void __launch_bounds__(256) wcomb_kernel(
    const float* __restrict__ gates, const float* __restrict__ ew,
    const float* __restrict__ eb, ushort* __restrict__ W_combT,
    float* __restrict__ b_comb) {
  __shared__ ushort wS[128 * 130];
  int g = blockIdx.x, t = threadIdx.x;  // 256 threads
  float g0 = gates[g * 4], g1 = gates[g * 4 + 1], g2 = gates[g * 4 + 2], g3 = gates[g * 4 + 3];
  for (int k = t; k < D * D; k += 256) {
    int d = k >> 7, o = k & 127;  // coalesced read over o
    float v = g0 * ew[k] + g1 * ew[16384 + k] + g2 * ew[32768 + k] + g3 * ew[49152 + k];
    wS[o * 130 + d] = f2bf(v);
  }
  __syncthreads();
  for (int k = t; k < D * D; k += 256) {
    int o = k >> 7, d = k & 127;  // coalesced write over d
    W_combT[(size_t)g * 16384 + k] = wS[o * 130 + d];
  }
  if (t < D)
    b_comb[g * D + t] = g0 * eb[t] + g1 * eb[D + t] + g2 * eb[2 * D + t] + g3 * eb[3 * D + t];
}

// ---------------- FFN weights -> bf16 transposed (k-contiguous) ----------------
static __global__ void prep_kernel(const float* __restrict__ w1, const float* __restrict__ w2,
                                   ushort* __restrict__ w1t, ushort* __restrict__ w2t) {
  int i = blockIdx.x * 256 + threadIdx.x;  // 32768 total
  { int j = i >> 7, d = i & 127; w1t[i] = f2bf(w1[(size_t)d * 256 + j]); }
  { int o = i >> 8, j = i & 255; w2t[i] = f2bf(w2[(size_t)j * 128 + o]); }
}

// ---------------- 3-phase prefix scan of node_deg -> rowoff, plus dinv + bucket bases ----------------
static __global__ void scanA_kernel(const int* __restrict__ node_deg, int* rowoff, int* blocksum, int N) {
  __shared__ int sS[1024];
  int t = threadIdx.x, i = blockIdx.x * 1024 + t;
  int v = (i < N) ? node_deg[i] : 0;
  sS[t] = v; __syncthreads();
  for (int off = 1; off < 1024; off <<= 1) {
    int add = (t >= off) ? sS[t - off] : 0;
    __syncthreads();
    sS[t] += add;
    __syncthreads();
  }
  if (i < N) rowoff[i + 1] = sS[t];
  if (t == 1023) blocksum[blockIdx.x] = sS[1023];
}

static __global__ void scanB_kernel(const int* __restrict__ blocksum, int* blockbase, int nb) {
  __shared__ int sS[128];
  int t = threadIdx.x;
  int v = (t < nb) ? blocksum[t] : 0;
  sS[t] = v; __syncthreads();
  for (int off = 1; off < 128; off <<= 1) {
    int add = (t >= off) ? sS[t - off] : 0;
    __syncthreads();
    sS[t] += add;
    __syncthreads();
  }
  blockbase[t] = sS[t] - v;  // exclusive
}

// finalizes rowoff; writes bucket cursors; folds per-graph degree stats
static __global__ void scanC_kernel(const int* __restrict__ node_deg, int* rowoff,
                                    const int* __restrict__ blockbase,
                                    float* dinv, const int* __restrict__ batch,
                                    int* bcur,
                                    float* gcnt, float* gdsum, unsigned* gdmaxE, int N) {
  int i = blockIdx.x * 256 + threadIdx.x;
  int nd = 0;
  if (i < N) {
    int incl = rowoff[i + 1] + blockbase[i >> 10];
    rowoff[i + 1] = incl;
    nd = node_deg[i];
    dinv[i] = rsqrtf((float)nd + 1.0f);
    if (i == 0) { rowoff[0] = 0; bcur[0] = 0; }
    if (((i + 1) & 511) == 0) bcur[(i + 1) >> 9] = incl;
  }
  int g = batch[min(i, N - 1)];
  float dv = (float)nd;
  int g0w = __shfl(g, 0);
  int waveLast = blockIdx.x * 256 + ((threadIdx.x >> 6) << 6) + 63;
  bool uni = (waveLast < N) && __all(g == g0w);
  if (uni) {
    float s = dv, mx = dv;
    for (int off = 32; off > 0; off >>= 1) { s += __shfl_down(s, off); mx = fmaxf(mx, __shfl_down(mx, off)); }
    if ((threadIdx.x & 63) == 0) {
      atomicAdd(&gcnt[g0w], 64.f);
      atomicAdd(&gdsum[g0w], s);
      atomicMax(&gdmaxE[g0w], encf(mx));
    }
  } else if (i < N) {
    atomicAdd(&gcnt[g], 1.f);
    atomicAdd(&gdsum[g], dv);
    atomicMax(&gdmaxE[g], encf(dv));
  }
}

// ---------------- CSR build pass A: coarse bucket sort by dst>>9, packed int ----------------
// packed edge = (src<<9) | (dst & 511). Assumes NB <= 256 (N <= 131072).
static __global__ void __launch_bounds__(256) fillA_kernel(
    const int* __restrict__ src, const int* __restrict__ dst,
    int* bcur, int* __restrict__ esort, int E) {
  __shared__ int histS[256], startS[256], cursorS[256], gbaseS[256];
  __shared__ int eS[4096];             // 16 KB packed
  __shared__ unsigned char bS[4096];   // bucket of each slot
  int t = threadIdx.x;
  int base = blockIdx.x * 4096;
  int cnt = min(4096, E - base);
  int srcR[16], dstR[16];
  histS[t] = 0;
  __syncthreads();
#pragma unroll
  for (int k = 0; k < 16; k++) {
    int e = base + k * 256 + t;
    if (e < E) { srcR[k] = src[e]; dstR[k] = dst[e]; }
    else dstR[k] = -1;
  }
#pragma unroll
  for (int k = 0; k < 16; k++)
    if (dstR[k] >= 0) atomicAdd(&histS[dstR[k] >> 9], 1);
  __syncthreads();
  int hv = histS[t];
  startS[t] = hv;
  __syncthreads();
  for (int off = 1; off < 256; off <<= 1) {
    int add = (t >= off) ? startS[t - off] : 0;
    __syncthreads();
    startS[t] += add;
    __syncthreads();
  }
  int excl = startS[t] - hv;
  __syncthreads();
  startS[t] = excl;
  cursorS[t] = excl;
  gbaseS[t] = (hv > 0) ? atomicAdd(&bcur[t], hv) : 0;
  __syncthreads();
#pragma unroll
  for (int k = 0; k < 16; k++)
    if (dstR[k] >= 0) {
      int b = dstR[k] >> 9;
      int p = atomicAdd(&cursorS[b], 1);
      eS[p] = (srcR[k] << 9) | (dstR[k] & 511);
      bS[p] = (unsigned char)b;
    }
  __syncthreads();
  for (int k = t; k < cnt; k += 256) {
    int b = bS[k];
    esort[gbaseS[b] + (k - startS[b])] = eS[k];
  }
}

// ---------------- CSR build pass B: per-bucket fine fill, LDS cursors ----------------
static __global__ void __launch_bounds__(256) fillB_kernel(
    const int* __restrict__ esort, const int* __restrict__ rowoff,
    int* __restrict__ csr_src, int N) {
  __shared__ int curS[512];
  int b = blockIdx.x, t = threadIdx.x;
  int n0 = b << 9, n1 = min(n0 + 512, N);
  int nn = n1 - n0;
  for (int i = t; i < nn; i += 256) curS[i] = rowoff[n0 + i];
  int r0 = rowoff[n0], r1 = rowoff[n1];
  __syncthreads();
  for (int e = r0 + t; e < r1; e += 256) {
    int v = esort[e];
    int p = atomicAdd(&curS[v & 511], 1);
    csr_src[p] = v >> 9;
  }
}

// ---------------- GCN aggregation: one WAVE per node, bf16 rows, 4-deep unroll ----------------
static __global__ void __launch_bounds__(256) gather_kernel(
    const ushort2* __restrict__ xb2, const int* __restrict__ rowoff,
    const int* __restrict__ csr_src, const float* __restrict__ dinv,
    ushort2* __restrict__ aggB2, int N) {
  __shared__ int eS[4][64];
  __shared__ float cS[4][64];
  int t = threadIdx.x, w = t >> 6, l = t & 63;
  int n = blockIdx.x * 4 + w;
  if (n >= N) return;
  int r0 = rowoff[n], r1 = rowoff[n + 1];
  float dn = dinv[n];
  ushort2 xv = xb2[(size_t)n * 64 + l];
  float2 acc = { bf2f(xv.x) * dn, bf2f(xv.y) * dn };
  for (int j0 = r0; j0 < r1; j0 += 64) {
    int cnt = min(64, r1 - j0);
    if (j0 + l < r1) { int s = csr_src[j0 + l]; eS[w][l] = s; cS[w][l] = dinv[s]; }
    int k = 0;
    for (; k + 4 <= cnt; k += 4) {  // 4 independent row loads in flight
      int s0 = eS[w][k], s1 = eS[w][k + 1], s2 = eS[w][k + 2], s3 = eS[w][k + 3];
      float c0 = cS[w][k], c1 = cS[w][k + 1], c2 = cS[w][k + 2], c3 = cS[w][k + 3];
      ushort2 v0 = xb2[(size_t)s0 * 64 + l];
      ushort2 v1 = xb2[(size_t)s1 * 64 + l];
      ushort2 v2 = xb2[(size_t)s2 * 64 + l];
      ushort2 v3 = xb2[(size_t)s3 * 64 + l];
      acc.x += bf2f(v0.x) * c0; acc.y += bf2f(v0.y) * c0;
      acc.x += bf2f(v1.x) * c1; acc.y += bf2f(v1.y) * c1;
      acc.x += bf2f(v2.x) * c2; acc.y += bf2f(v2.y) * c2;
      acc.x += bf2f(v3.x) * c3; acc.y += bf2f(v3.y) * c3;
    }
    for (; k < cnt; k++) {
      int s = eS[w][k]; float cc = cS[w][k];
      ushort2 sv = xb2[(size_t)s * 64 + l];
      acc.x += bf2f(sv.x) * cc; acc.y += bf2f(sv.y) * cc;
    }
  }
  ushort2 o; o.x = f2bf(acc.x * dn); o.y = f2bf(acc.y * dn);
  aggB2[(size_t)n * 64 + l] = o;
}

// ---------------- gated expert combine + residual (MFMA bf16) ----------------
// aggB (bf16) in, hB (bf16) out. BN1 sums -> replicated slot (blockIdx & 63).
static __global__ void __launch_bounds__(256) expert_kernel(
    const ushort* __restrict__ aggB, const float* __restrict__ x, const int* __restrict__ batch,
    const ushort* __restrict__ W_combT, const float* __restrict__ b_comb,
    ushort* __restrict__ hB, float* bn1s, float* bn1s2, int N) {
  __shared__ __align__(16) ushort aggS[64 * 136];
  __shared__ int bS[64];
  int t = threadIdx.x, n0 = blockIdx.x * 64;
  int tile = min(64, N - n0);
  for (int k = t; k < 64 * 16; k += 256) {  // short8 copies, no convert
    int i = k >> 4, c = (k & 15) * 8;
    short8 v = (short8){0, 0, 0, 0, 0, 0, 0, 0};
    if (i < tile) v = *(const short8*)&aggB[(size_t)(n0 + i) * D + c];
    *(short8*)&aggS[i * 136 + c] = v;
  }
  if (t < 64) bS[t] = batch[min(n0 + t, N - 1)];
  __syncthreads();
  int w = t >> 6, ln = t & 15, quad = (t & 63) >> 4;
  float s[2] = {0.f, 0.f}, s2[2] = {0.f, 0.f};
  int mstart = 0;
  while (mstart < tile) {
    int g = bS[mstart];
    int mend = mstart + 1;
    while (mend < tile && bS[mend] == g) mend++;
    f32x4 acc[4][2];
#pragma unroll
    for (int mi = 0; mi < 4; mi++)
#pragma unroll
      for (int ni = 0; ni < 2; ni++) acc[mi][ni] = (f32x4){0.f, 0.f, 0.f, 0.f};
    const ushort* Wg = W_combT + (size_t)g * 16384;
#pragma unroll
    for (int ks = 0; ks < 4; ks++) {
      int kk = ks * 32 + quad * 8;
      short8 a[4], b[2];
#pragma unroll
      for (int mi = 0; mi < 4; mi++) a[mi] = *(const short8*)&aggS[(mi * 16 + ln) * 136 + kk];
#pragma unroll
      for (int ni = 0; ni < 2; ni++) b[ni] = *(const short8*)&Wg[(size_t)(w * 32 + ni * 16 + ln) * 128 + kk];
#pragma unroll
      for (int mi = 0; mi < 4; mi++)
#pragma unroll
        for (int ni = 0; ni < 2; ni++)
          acc[mi][ni] = __builtin_amdgcn_mfma_f32_16x16x32_bf16(a[mi], b[ni], acc[mi][ni], 0, 0, 0);
    }
    float bias[2];
#pragma unroll
    for (int ni = 0; ni < 2; ni++) bias[ni] = b_comb[g * D + w * 32 + ni * 16 + ln];
#pragma unroll
    for (int mi = 0; mi < 4; mi++)
#pragma unroll
      for (int r = 0; r < 4; r++) {
        int m = mi * 16 + quad * 4 + r;
        if (m >= mstart && m < mend) {
          size_t rowoff_ = (size_t)(n0 + m) * D;
#pragma unroll
          for (int ni = 0; ni < 2; ni++) {
            int o = w * 32 + ni * 16 + ln;
            float hv = x[rowoff_ + o] + acc[mi][ni][r] + bias[ni];
            hB[rowoff_ + o] = f2bf(hv);
            s[ni] += hv; s2[ni] += hv * hv;
          }
        }
      }
    mstart = mend;
  }
#pragma unroll
  for (int ni = 0; ni < 2; ni++) {
    s[ni] += __shfl_down(s[ni], 32);  s[ni] += __shfl_down(s[ni], 16);
    s2[ni] += __shfl_down(s2[ni], 32); s2[ni] += __shfl_down(s2[ni], 16);
  }
  if (quad == 0) {
    int slot = (blockIdx.x & (NREP - 1)) * D;
#pragma unroll
    for (int ni = 0; ni < 2; ni++) {
      int o = w * 32 + ni * 16 + ln;
      atomicAdd(&bn1s[slot + o], s[ni]);
      atomicAdd(&bn1s2[slot + o], s2[ni]);
    }
  }
}

// ---------------- bn finalize: reduce 64 replicas -> fused scale/shift ----------------
static __global__ void bnfin_kernel(const float* s, const float* s2,
                                    const float* __restrict__ g, const float* __restrict__ b,
                                    float* sc, float* sh, float invN) {
  int t = threadIdx.x;
  if (t < D) {
    float st = 0.f, s2t = 0.f;
    for (int k = 0; k < NREP; k++) { st += s[k * D + t]; s2t += s2[k * D + t]; }
    float m = st * invN;
    float var = s2t * invN - m * m;
    float rstd = rsqrtf(var + EPSV);
    float scv = rstd * g[t];
    sc[t] = scv;
    sh[t] = b[t] - m * scv;
  }
}

// ---------------- FFN (MFMA bf16), M=64, in-place on hB (tile staged to LDS first) ----------------
static __global__ void __launch_bounds__(256) ffn_kernel(
    ushort* __restrict__ hB, const float* __restrict__ sc1, const float* __restrict__ sh1,
    const ushort* __restrict__ w1t, const float* __restrict__ fb1,
    const ushort* __restrict__ w2t, const float* __restrict__ fb2,
    float* bn2s, float* bn2s2, int N) {
  __shared__ __align__(16) ushort kvnS[64 * 136];   // 17 KB
  __shared__ __align__(16) ushort hidS[64 * 264];   // 34 KB
  int t = threadIdx.x, n0 = blockIdx.x * 64;
  int tile = min(64, N - n0);
  for (int k = t; k < 64 * 64; k += 256) {
    int i = k >> 6, dp = (k & 63) * 2;
    float vx = 0.f, vy = 0.f;
    if (i < tile) {
      ushort2 hv = *(const ushort2*)&hB[(size_t)(n0 + i) * D + dp];
      vx = bf2f(hv.x) * sc1[dp] + sh1[dp];
      vy = bf2f(hv.y) * sc1[dp + 1] + sh1[dp + 1];
    }
    kvnS[i * 136 + dp] = f2bf(vx);
    kvnS[i * 136 + dp + 1] = f2bf(vy);
  }
  __syncthreads();
  int w = t >> 6, ln = t & 15, quad = (t & 63) >> 4;
  // ---- GEMM1: hidden[64x256] = kvn[64x128] @ w1[128x256]
  f32x4 acc1[4][4];
#pragma unroll
  for (int mi = 0; mi < 4; mi++)
#pragma unroll
    for (int ni = 0; ni < 4; ni++) acc1[mi][ni] = (f32x4){0.f, 0.f, 0.f, 0.f};
#pragma unroll
  for (int ks = 0; ks < 4; ks++) {
    int kk = ks * 32 + quad * 8;
    short8 a[4], b[4];
#pragma unroll
    for (int mi = 0; mi < 4; mi++) a[mi] = *(const short8*)&kvnS[(mi * 16 + ln) * 136 + kk];
#pragma unroll
    for (int ni = 0; ni < 4; ni++) b[ni] = *(const short8*)&w1t[(size_t)(w * 64 + ni * 16 + ln) * 128 + kk];
#pragma unroll
    for (int mi = 0; mi < 4; mi++)
#pragma unroll
      for (int ni = 0; ni < 4; ni++)
        acc1[mi][ni] = __builtin_amdgcn_mfma_f32_16x16x32_bf16(a[mi], b[ni], acc1[mi][ni], 0, 0, 0);
  }
  float bias1[4];
#pragma unroll
  for (int ni = 0; ni < 4; ni++) bias1[ni] = fb1[w * 64 + ni * 16 + ln];
#pragma unroll
  for (int mi = 0; mi < 4; mi++)
#pragma unroll
    for (int ni = 0; ni < 4; ni++)
#pragma unroll
      for (int r = 0; r < 4; r++) {
        int mrow = mi * 16 + quad * 4 + r;
        int j = w * 64 + ni * 16 + ln;
        hidS[mrow * 264 + j] = f2bf(fmaxf(acc1[mi][ni][r] + bias1[ni], 0.f));
      }
  __syncthreads();
  // ---- GEMM2: out[64x128] = hidden[64x256] @ w2[256x128]
  f32x4 acc2[4][2];
#pragma unroll
  for (int mi = 0; mi < 4; mi++)
#pragma unroll
    for (int ni = 0; ni < 2; ni++) acc2[mi][ni] = (f32x4){0.f, 0.f, 0.f, 0.f};
#pragma unroll
  for (int ks = 0; ks < 8; ks++) {
    int kk = ks * 32 + quad * 8;
    short8 a[4], b[2];
#pragma unroll
    for (int mi = 0; mi < 4; mi++) a[mi] = *(const short8*)&hidS[(mi * 16 + ln) * 264 + kk];
#pragma unroll
    for (int ni = 0; ni < 2; ni++) b[ni] = *(const short8*)&w2t[(size_t)(w * 32 + ni * 16 + ln) * 256 + kk];
#pragma unroll
    for (int mi = 0; mi < 4; mi++)
#pragma unroll
      for (int ni = 0; ni < 2; ni++)
        acc2[mi][ni] = __builtin_amdgcn_mfma_f32_16x16x32_bf16(a[mi], b[ni], acc2[mi][ni], 0, 0, 0);
  }
  float bias2[2];
#pragma unroll
  for (int ni = 0; ni < 2; ni++) bias2[ni] = fb2[w * 32 + ni * 16 + ln];
  float s[2] = {0.f, 0.f}, s2[2] = {0.f, 0.f};
#pragma unroll
  for (int mi = 0; mi < 4; mi++)
#pragma unroll
    for (int r = 0; r < 4; r++) {
      int mrow = mi * 16 + quad * 4 + r;
      if (mrow < tile) {
        size_t rowoff_ = (size_t)(n0 + mrow) * D;
#pragma unroll
        for (int ni = 0; ni < 2; ni++) {
          int o = w * 32 + ni * 16 + ln;
          float v = bf2f(kvnS[mrow * 136 + o]) + acc2[mi][ni][r] + bias2[ni];
          hB[rowoff_ + o] = f2bf(v);  // in-place: tile already staged in kvnS
          s[ni] += v; s2[ni] += v * v;
        }
      }
    }
#pragma unroll
  for (int ni = 0; ni < 2; ni++) {
    s[ni] += __shfl_down(s[ni], 32);  s[ni] += __shfl_down(s[ni], 16);
    s2[ni] += __shfl_down(s2[ni], 32); s2[ni] += __shfl_down(s2[ni], 16);
  }
  if (quad == 0) {
    int slot = (blockIdx.x & (NREP - 1)) * D;
#pragma unroll
    for (int ni = 0; ni < 2; ni++) {
      int o = w * 32 + ni * 16 + ln;
      atomicAdd(&bn2s[slot + o], s[ni]);
      atomicAdd(&bn2s2[slot + o], s2[ni]);
    }
  }
}

// ---------------- final bn2 apply: bf16 in -> fp32 out, fused scale/shift ----------------
static __global__ void bnapply_kernel(const ushort* __restrict__ hB, float* __restrict__ out,
                                      const float* __restrict__ sc, const float* __restrict__ sh,
                                      int total) {
  int i = blockIdx.x * 256 + threadIdx.x;
  if (i < total) {
    int d = i & 127;
    out[i] = bf2f(hB[i]) * sc[d] + sh[d];
  }
}

extern "C" void kernel_launch(void* const* d_in, const int* in_sizes, int n_in,
                              void* d_out, int out_size, void* d_ws, size_t ws_size,
                              hipStream_t stream) {
  (void)n_in; (void)out_size; (void)ws_size;
  const float* x    = (const float*)d_in[0];
  const int*   ei   = (const int*)d_in[1];
  const int*   batch= (const int*)d_in[2];
  const float* temp = (const float*)d_in[3];
  const float* rw1  = (const float*)d_in[4];
  const float* rb1  = (const float*)d_in[5];
  const float* rw2  = (const float*)d_in[6];
  const float* rb2  = (const float*)d_in[7];
  const float* rw3  = (const float*)d_in[8];
  const float* rb3  = (const float*)d_in[9];
  const float* ew   = (const float*)d_in[10];
  const float* eb   = (const float*)d_in[11];
  const float* bn1g = (const float*)d_in[12];
  const float* bn1b = (const float*)d_in[13];
  const float* fw1  = (const float*)d_in[14];
  const float* fb1  = (const float*)d_in[15];
  const float* fw2  = (const float*)d_in[16];
  const float* fb2  = (const float*)d_in[17];
  const float* bn2g = (const float*)d_in[18];
  const float* bn2b = (const float*)d_in[19];

  int N = in_sizes[0] / D;
  int E = in_sizes[1] / 2;
  const int* src = ei;
  const int* dst = ei + E;

  // d_out doubles as scratch: x_bf | aggB (2 x N*D*2 bytes = exactly out size);
  // both dead before bnapply overwrites d_out with the fp32 result.
  ushort* x_bf = (ushort*)d_out;
  ushort* aggB = (ushort*)((char*)d_out + (size_t)N * D * 2);

  char* p = (char*)d_ws;
  auto alloc = [&](size_t bytes) -> void* {
    void* r = (void*)p;
    p += (bytes + 255) & ~(size_t)255;
    return r;
  };
  int NB = (N + 511) >> 9;  // 512-node buckets (assumes NB <= 256)
  int*   node_deg = (int*)alloc((size_t)N * 4);
  int*   rowoff   = (int*)alloc(((size_t)N + 1) * 4);
  int*   csr_src  = (int*)alloc((size_t)E * 4);
  int*   esort    = (int*)alloc((size_t)E * 4);
  int*   bcur     = (int*)alloc(((size_t)NB + 1) * 4);
  int*   blocksum = (int*)alloc(128 * 4);
  int*   blockbase= (int*)alloc(128 * 4);
  float* dinv     = (float*)alloc((size_t)N * 4);
  ushort* hB      = (ushort*)alloc((size_t)N * D * 2);
  float* gsum     = (float*)alloc((size_t)B * D * 4);
  unsigned* gmaxE = (unsigned*)alloc((size_t)B * D * 4);
  float* gcnt     = (float*)alloc((size_t)B * 4);
  float* gdsum    = (float*)alloc((size_t)B * 4);
  unsigned* gdmaxE= (unsigned*)alloc((size_t)B * 4);
  float* gates    = (float*)alloc((size_t)B * 4 * 4);
  float* b_comb   = (float*)alloc((size_t)B * D * 4);
  float* bn1s     = (float*)alloc((size_t)NREP * D * 4);
  float* bn1s2    = (float*)alloc((size_t)NREP * D * 4);
  float* sc1      = (float*)alloc(D * 4);
  float* sh1      = (float*)alloc(D * 4);
  float* bn2s     = (float*)alloc((size_t)NREP * D * 4);
  float* bn2s2    = (float*)alloc((size_t)NREP * D * 4);
  float* sc2      = (float*)alloc(D * 4);
  float* sh2      = (float*)alloc(D * 4);
  ushort* W_combT = (ushort*)alloc((size_t)B * D * D * 2);
  ushort* w1t     = (ushort*)alloc((size_t)D * 256 * 2);
  ushort* w2t     = (ushort*)alloc((size_t)D * 256 * 2);

  init_kernel<<<(N + 255) / 256, 256, 0, stream>>>(node_deg, bn1s, bn1s2, bn2s, bn2s2,
                                                   gsum, gmaxE, gcnt, gdsum, gdmaxE, N);
  deg_kernel<<<(E + 255) / 256, 256, 0, stream>>>(dst, node_deg, E);
  prep_kernel<<<128, 256, 0, stream>>>(fw1, fw2, w1t, w2t);
  statspart_kernel<<<(N + 63) / 64, 128, 0, stream>>>(x, batch, gsum, gmaxE, x_bf, N);
  int nb = (N + 1023) / 1024;
  scanA_kernel<<<nb, 1024, 0, stream>>>(node_deg, rowoff, blocksum, N);
  scanB_kernel<<<1, 128, 0, stream>>>(blocksum, blockbase, nb);
  scanC_kernel<<<(N + 255) / 256, 256, 0, stream>>>(node_deg, rowoff, blockbase, dinv,
                                                    batch, bcur, gcnt, gdsum, gdmaxE, N);
  router_kernel<<<B, 128, 0, stream>>>(gsum, gmaxE, gcnt, gdsum, gdmaxE,
                                       rw1, rb1, rw2, rb2, rw3, rb3, temp, gates);
  wcomb_kernel<<<B, 256, 0, stream>>>(gates, ew, eb, W_combT, b_comb);
  fillA_kernel<<<(E + 4095) / 4096, 256, 0, stream>>>(src, dst, bcur, esort, E);
  fillB_kernel<<<NB, 256, 0, stream>>>(esort, rowoff, csr_src, N);
  gather_kernel<<<(N + 3) / 4, 256, 0, stream>>>((const ushort2*)x_bf, rowoff, csr_src, dinv,
                                                 (ushort2*)aggB, N);
  int nb64 = (N + 63) / 64;
  expert_kernel<<<nb64, 256, 0, stream>>>(aggB, x, batch, W_combT, b_comb, hB, bn1s, bn1s2, N);
  bnfin_kernel<<<1, 128, 0, stream>>>(bn1s, bn1s2, bn1g, bn1b, sc1, sh1, 1.0f / (float)N);
  ffn_kernel<<<nb64, 256, 0, stream>>>(hB, sc1, sh1, w1t, fb1, w2t, fb2, bn2s, bn2s2, N);
  bnfin_kernel<<<1, 128, 0, stream>>>(bn2s, bn2s2, bn2g, bn2b, sc2, sh2, 1.0f / (float)N);
  bnapply_kernel<<<((size_t)N * D + 255) / 256, 256, 0, stream>>>(hB, (float*)d_out, sc2, sh2, N * D);
}